// Round 5
// baseline (2470.857 us; speedup 1.0000x reference)
//
#include <hip/hip_runtime.h>
#include <hip/hip_bf16.h>
#include <stdint.h>

// SememeRGCN on MI355X — fully fused per-layer kernel.
// Block owns 64 dst nodes. For t = 0 (root) stage x rows into fp32 LDS;
// for t = 1..8 edge-parallel gather-sum x[src] rows into fp32 LDS via
// ds_add_f32 (edges pre-sorted by (dst/64, t, dst%64) so each (block,t)
// range is contiguous in csr), then MFMA vs W_t (scale by invc + cvt bf16
// at fragment load). LN+ReLU fused in epilogue. The [N,8,128] mean tensor
// never touches HBM (was 100MB write + 100MB read per layer in r4).
// x ping-pongs between two 12.8MB buffers (L3-resident -> cheap gathers).

#define N_NODES 50000
#define N_EDGES 800000
#define R_REL 8
#define MT 64                         // nodes per block
#define NBLK ((N_NODES + MT - 1) / MT)          // 782
#define NSEG2 (NBLK * 512)                      // 400384 (block*512 + t*64 + dloc)
#define KTOT 1152
#define SMS 132                       // meanS stride (floats): 2-way bank alias only
#define BS_S 136                      // Bs stride (shorts)

typedef __bf16 bf16_8 __attribute__((ext_vector_type(8)));
typedef float floatx4 __attribute__((ext_vector_type(4)));
typedef unsigned short ushort8 __attribute__((ext_vector_type(8)));

static __device__ __forceinline__ float bf2f(unsigned short v) {
    unsigned u = ((unsigned)v) << 16;
    return __builtin_bit_cast(float, u);
}
static __device__ __forceinline__ unsigned short f2bf(float f) {
    unsigned u = __builtin_bit_cast(unsigned, f);
    u += 0x7FFFu + ((u >> 16) & 1u);   // round-to-nearest-even
    return (unsigned short)(u >> 16);
}

// ---------------- preprocessing ----------------

// zero cnt/cursor region + detect dtype (g1 all-ones: fp32 dw0=0x3F800000)
__global__ void k_init(unsigned* __restrict__ p, int n_words,
                       const unsigned* __restrict__ g1, unsigned* __restrict__ flag) {
    int i = blockIdx.x * blockDim.x + threadIdx.x;
    if (i == 0) flag[0] = (g1[0] == 0x3F803F80u) ? 1u : 0u;
    int stride = gridDim.x * blockDim.x;
    for (; i < n_words; i += stride) p[i] = 0u;
}

__global__ void k_count(const int* __restrict__ ei, const int* __restrict__ et,
                        unsigned* __restrict__ cnt_nt) {
    int e = blockIdx.x * 256 + threadIdx.x;
    if (e >= N_EDGES) return;
    int dst = ei[N_EDGES + e];
    int t = et[e];
    int seg = (dst >> 6) * 512 + t * 64 + (dst & 63);
    atomicAdd(&cnt_nt[seg], 1u);
}

#define SCAN_B 1024
#define SCAN_NB (NSEG2 / SCAN_B)   // 391 exactly

__global__ void k_scan1(const unsigned* __restrict__ cnt, unsigned* __restrict__ escan,
                        unsigned* __restrict__ bsum) {
    __shared__ unsigned wsum[16];
    int tid = threadIdx.x;
    int lane = tid & 63, wid = tid >> 6;
    int i = blockIdx.x * SCAN_B + tid;
    unsigned v = (i < NSEG2) ? cnt[i] : 0u;
    unsigned incl = v;
#pragma unroll
    for (int d = 1; d < 64; d <<= 1) {
        unsigned t = __shfl_up(incl, d, 64);
        if (lane >= d) incl += t;
    }
    if (lane == 63) wsum[wid] = incl;
    __syncthreads();
    if (wid == 0 && lane < 16) {
        unsigned w = wsum[lane];
#pragma unroll
        for (int d = 1; d < 16; d <<= 1) {
            unsigned t = __shfl_up(w, d, 64);
            if (lane >= d) w += t;
        }
        wsum[lane] = w;
    }
    __syncthreads();
    unsigned woff = (wid == 0) ? 0u : wsum[wid - 1];
    if (i < NSEG2) escan[i] = woff + incl - v;
    if (tid == 0) bsum[blockIdx.x] = wsum[15];
}

__global__ void k_scan2(const unsigned* __restrict__ bsum, unsigned* __restrict__ boff) {
    __shared__ unsigned wls[8];
    int tid = threadIdx.x, lane = tid & 63, wid = tid >> 6;   // 512 threads
    unsigned v = (tid < SCAN_NB) ? bsum[tid] : 0u;
    unsigned incl = v;
#pragma unroll
    for (int d = 1; d < 64; d <<= 1) {
        unsigned t = __shfl_up(incl, d, 64);
        if (lane >= d) incl += t;
    }
    if (lane == 63) wls[wid] = incl;
    __syncthreads();
    if (wid == 0 && lane < 8) {
        unsigned w = wls[lane];
#pragma unroll
        for (int d = 1; d < 8; d <<= 1) {
            unsigned t = __shfl_up(w, d, 64);
            if (lane >= d) w += t;
        }
        wls[lane] = w;
    }
    __syncthreads();
    unsigned woff = wid ? wls[wid - 1] : 0u;
    if (tid < SCAN_NB) boff[tid] = woff + incl - v;
}

// offs + invc in one pass
__global__ void k_scan3(const unsigned* __restrict__ escan, const unsigned* __restrict__ boff,
                        unsigned* __restrict__ offs, const unsigned* __restrict__ cnt,
                        float* __restrict__ invc) {
    int i = blockIdx.x * SCAN_B + threadIdx.x;
    if (i < NSEG2) {
        offs[i] = escan[i] + boff[blockIdx.x];
        unsigned c = cnt[i];
        invc[i] = 1.0f / (float)(c ? c : 1u);
    }
    if (i == 0) offs[NSEG2] = N_EDGES;
}

__global__ void k_fill(const int* __restrict__ ei, const int* __restrict__ et,
                       const unsigned* __restrict__ offs, unsigned* __restrict__ cursor,
                       unsigned* __restrict__ csr) {
    int e = blockIdx.x * 256 + threadIdx.x;
    if (e >= N_EDGES) return;
    int src = ei[e];
    int dst = ei[N_EDGES + e];
    int t = et[e];
    int seg = (dst >> 6) * 512 + t * 64 + (dst & 63);
    unsigned pos = offs[seg] + atomicAdd(&cursor[seg], 1u);
    csr[pos] = (unsigned)src | ((unsigned)(dst & 63) << 16);
}

// merged: WcatT build (transpose to o-major) + 7 param-vector fp32 copies
#define WELEMS (3 * 128 * KTOT)
__global__ void k_prep(const unsigned* __restrict__ flag,
                       const void* __restrict__ W1, const void* __restrict__ r1,
                       const void* __restrict__ W2, const void* __restrict__ r2,
                       const void* __restrict__ W3, const void* __restrict__ r3,
                       unsigned short* __restrict__ WT,
                       const void* p0, const void* p1, const void* p2,
                       const void* p3, const void* p4, const void* p5,
                       const void* p6, float* __restrict__ vecs) {
    int idx = blockIdx.x * 256 + threadIdx.x;
    int is_bf = (int)flag[0];
    if (idx < WELEMS) {
        int l = idx / (128 * KTOT);
        int rem = idx - l * (128 * KTOT);
        int o = rem / KTOT, k = rem - o * KTOT;
        const void* W = (l == 0) ? W1 : (l == 1) ? W2 : W3;
        const void* rt = (l == 0) ? r1 : (l == 1) ? r2 : r3;
        size_t eoff;
        const void* src;
        if (k < 128) { src = rt; eoff = (size_t)k * 128 + o; }
        else {
            int t = (k - 128) >> 7, kk = (k - 128) & 127;
            src = W; eoff = (size_t)t * 16384 + (size_t)kk * 128 + o;
        }
        WT[idx] = is_bf ? ((const unsigned short*)src)[eoff]
                        : f2bf(((const float*)src)[eoff]);
    } else if (idx < WELEMS + 7 * 128) {
        int v = (idx - WELEMS) >> 7, i = (idx - WELEMS) & 127;
        const void* p = (v == 0) ? p0 : (v == 1) ? p1 : (v == 2) ? p2 :
                        (v == 3) ? p3 : (v == 4) ? p4 : (v == 5) ? p5 : p6;
        vecs[v * 128 + i] = is_bf ? bf2f(((const unsigned short*)p)[i])
                                  : ((const float*)p)[i];
    }
}

// gather emb[node_ids] -> xa (bf16)
__global__ void k_gather(const unsigned* __restrict__ flag,
                         const int* __restrict__ ids, const void* __restrict__ emb,
                         unsigned short* __restrict__ x) {
    int c = blockIdx.x * 256 + threadIdx.x;
    if (c >= N_NODES * 32) return;
    int is_bf = (int)flag[0];
    int row = c >> 5, k = (c & 31) << 2;
    size_t s = (size_t)ids[row] * 128 + k;
    if (is_bf) {
        *(uint2*)&x[(size_t)row * 128 + k] = *(const uint2*)((const unsigned short*)emb + s);
    } else {
        const float4 f = *(const float4*)((const float*)emb + s);
        uint2 u;
        u.x = (unsigned)f2bf(f.x) | ((unsigned)f2bf(f.y) << 16);
        u.y = (unsigned)f2bf(f.z) | ((unsigned)f2bf(f.w) << 16);
        *(uint2*)&x[(size_t)row * 128 + k] = u;
    }
}

// ---------------- fused layer kernel ----------------
// grid NBLK (782), 256 threads. LDS: meanS 33.8KB + Bs 34.8KB + red 1KB = 69KB
// -> 2 blocks/CU. Waves: wm=(wave&1)*32 (M half), wn=(wave>>1)*64 (N half).

__global__ __launch_bounds__(256, 2) void k_layer(
    const unsigned short* __restrict__ x,    // [N,128] bf16 input
    const unsigned short* __restrict__ WT,   // [128 o][1152 k] bf16
    const unsigned* __restrict__ offs,       // [NSEG2+1]
    const unsigned* __restrict__ csr,        // [E] src | dloc<<16
    const float* __restrict__ invc,          // [NSEG2]
    const float* __restrict__ bias,
    const float* __restrict__ g,
    const float* __restrict__ be,
    void* __restrict__ outp,                 // bf16 x_out or d_out
    int do_ln,
    const unsigned* __restrict__ flag)
{
    __shared__ float meanS[MT * SMS];
    __shared__ unsigned short Bs[128 * BS_S];
    __shared__ float sred[2][MT];
    __shared__ float qred[2][MT];

    int tid = threadIdx.x, b = blockIdx.x;
    int m0 = b * MT;
    int lane = tid & 63, wave = tid >> 6;
    int wm = (wave & 1) * 32, wn = (wave >> 1) * 64;
    int rr = lane & 15, qq = lane >> 4;
    int wnidx = wave >> 1;
    int c0 = lane * 2;

    floatx4 acc[2][4];
#pragma unroll
    for (int i = 0; i < 2; i++)
#pragma unroll
        for (int j = 0; j < 4; j++) acc[i][j] = (floatx4){0.f, 0.f, 0.f, 0.f};

    for (int t = 0; t <= R_REL; ++t) {
        // stage Bs[o][k] = WT[o*1152 + t*128 + k]  (prev MFMA finished at loop-end barrier)
#pragma unroll
        for (int it = 0; it < 8; ++it) {
            int c = tid + it * 256;              // 2048 chunks of 8 bf16
            int o = c >> 4, kc = (c & 15) << 3;
            *(ushort8*)&Bs[o * BS_S + kc] = *(const ushort8*)&WT[(size_t)o * KTOT + t * 128 + kc];
        }
        if (t == 0) {
            // root phase: stage x rows as f32
#pragma unroll
            for (int it = 0; it < 8; ++it) {
                int c = tid + it * 256;          // 2048 chunks of 4 floats
                int row = c >> 5, c4 = (c & 31) << 2;
                int grow = m0 + row;
                if (grow >= N_NODES) grow = N_NODES - 1;
                uint2 u = *(const uint2*)&x[(size_t)grow * 128 + c4];
                float4 f;
                f.x = bf2f((unsigned short)(u.x & 0xFFFFu));
                f.y = bf2f((unsigned short)(u.x >> 16));
                f.z = bf2f((unsigned short)(u.y & 0xFFFFu));
                f.w = bf2f((unsigned short)(u.y >> 16));
                *(float4*)&meanS[row * SMS + c4] = f;
            }
            __syncthreads();
        } else {
            // zero accumulator tile
#pragma unroll
            for (int it = 0; it < 8; ++it) {
                int c = tid + it * 256;
                int row = c >> 5, c4 = (c & 31) << 2;
                *(float4*)&meanS[row * SMS + c4] = (float4){0.f, 0.f, 0.f, 0.f};
            }
            __syncthreads();
            // edge-parallel gather: wave processes 64-edge batches round-robin
            unsigned e0 = offs[b * 512 + (t - 1) * 64];
            unsigned e1 = offs[b * 512 + t * 64];
            for (unsigned cb = e0 + (unsigned)wave * 64u; cb < e1; cb += 256u) {
                int cnt = (int)min(64u, e1 - cb);
                unsigned pk = (lane < cnt) ? csr[cb + lane] : 0u;
                int j = 0;
                for (; j + 4 <= cnt; j += 4) {
                    unsigned p0 = __shfl(pk, j, 64);
                    unsigned p1 = __shfl(pk, j + 1, 64);
                    unsigned p2 = __shfl(pk, j + 2, 64);
                    unsigned p3 = __shfl(pk, j + 3, 64);
                    unsigned u0 = *(const unsigned*)&x[(size_t)(p0 & 0xFFFFu) * 128 + c0];
                    unsigned u1 = *(const unsigned*)&x[(size_t)(p1 & 0xFFFFu) * 128 + c0];
                    unsigned u2 = *(const unsigned*)&x[(size_t)(p2 & 0xFFFFu) * 128 + c0];
                    unsigned u3 = *(const unsigned*)&x[(size_t)(p3 & 0xFFFFu) * 128 + c0];
                    float* q0 = &meanS[(p0 >> 16) * SMS + c0];
                    float* q1 = &meanS[(p1 >> 16) * SMS + c0];
                    float* q2 = &meanS[(p2 >> 16) * SMS + c0];
                    float* q3 = &meanS[(p3 >> 16) * SMS + c0];
                    atomicAdd(q0,     bf2f((unsigned short)(u0 & 0xFFFFu)));
                    atomicAdd(q0 + 1, bf2f((unsigned short)(u0 >> 16)));
                    atomicAdd(q1,     bf2f((unsigned short)(u1 & 0xFFFFu)));
                    atomicAdd(q1 + 1, bf2f((unsigned short)(u1 >> 16)));
                    atomicAdd(q2,     bf2f((unsigned short)(u2 & 0xFFFFu)));
                    atomicAdd(q2 + 1, bf2f((unsigned short)(u2 >> 16)));
                    atomicAdd(q3,     bf2f((unsigned short)(u3 & 0xFFFFu)));
                    atomicAdd(q3 + 1, bf2f((unsigned short)(u3 >> 16)));
                }
                for (; j < cnt; ++j) {
                    unsigned p = __shfl(pk, j, 64);
                    unsigned u = *(const unsigned*)&x[(size_t)(p & 0xFFFFu) * 128 + c0];
                    float* q = &meanS[(p >> 16) * SMS + c0];
                    atomicAdd(q,     bf2f((unsigned short)(u & 0xFFFFu)));
                    atomicAdd(q + 1, bf2f((unsigned short)(u >> 16)));
                }
            }
            __syncthreads();
        }

        // MFMA phase: scale rows by invc (t>0), cvt to bf16 at frag load
        float wv0 = 1.f, wv1 = 1.f;
        if (t > 0) {
            wv0 = invc[b * 512 + (t - 1) * 64 + wm + rr];
            wv1 = invc[b * 512 + (t - 1) * 64 + wm + 16 + rr];
        }
#pragma unroll
        for (int kk = 0; kk < 4; ++kk) {
            int kb = kk * 32 + qq * 8;
            bf16_8 a[2], bfr[4];
#pragma unroll
            for (int i = 0; i < 2; ++i) {
                const float* ap = &meanS[(wm + i * 16 + rr) * SMS + kb];
                floatx4 f0 = *(const floatx4*)ap;
                floatx4 f1 = *(const floatx4*)(ap + 4);
                float wv = i ? wv1 : wv0;
                ushort8 av;
                av[0] = f2bf(f0[0] * wv); av[1] = f2bf(f0[1] * wv);
                av[2] = f2bf(f0[2] * wv); av[3] = f2bf(f0[3] * wv);
                av[4] = f2bf(f1[0] * wv); av[5] = f2bf(f1[1] * wv);
                av[6] = f2bf(f1[2] * wv); av[7] = f2bf(f1[3] * wv);
                a[i] = __builtin_bit_cast(bf16_8, av);
            }
#pragma unroll
            for (int jj = 0; jj < 4; ++jj)
                bfr[jj] = __builtin_bit_cast(bf16_8, *(const ushort8*)&Bs[(wn + jj * 16 + rr) * BS_S + kb]);
#pragma unroll
            for (int i = 0; i < 2; ++i)
#pragma unroll
                for (int jj = 0; jj < 4; ++jj)
                    acc[i][jj] = __builtin_amdgcn_mfma_f32_16x16x32_bf16(a[i], bfr[jj], acc[i][jj], 0, 0, 0);
        }
        __syncthreads();
    }

    // ---------------- epilogue ----------------
    if (do_ln) {
#pragma unroll
        for (int i = 0; i < 2; i++) {
#pragma unroll
            for (int p = 0; p < 4; p++) {
                float s1 = 0.f, s2 = 0.f;
#pragma unroll
                for (int j = 0; j < 4; j++) {
                    float v = acc[i][j][p] + bias[wn + j * 16 + rr];
                    s1 += v; s2 += v * v;
                }
#pragma unroll
                for (int d = 1; d < 16; d <<= 1) {
                    s1 += __shfl_xor(s1, d, 64);
                    s2 += __shfl_xor(s2, d, 64);
                }
                if (rr == 0) {
                    int rl = wm + i * 16 + qq * 4 + p;
                    sred[wnidx][rl] = s1;
                    qred[wnidx][rl] = s2;
                }
            }
        }
        __syncthreads();
        unsigned short* xo = (unsigned short*)outp;
#pragma unroll
        for (int i = 0; i < 2; i++) {
#pragma unroll
            for (int p = 0; p < 4; p++) {
                int rl = wm + i * 16 + qq * 4 + p;
                int grow = m0 + rl;
                float s1 = sred[0][rl] + sred[1][rl];
                float s2 = qred[0][rl] + qred[1][rl];
                float mu = s1 * (1.f / 128.f);
                float var = s2 * (1.f / 128.f) - mu * mu;
                float rs = rsqrtf(var + 1e-5f);
                if (grow < N_NODES) {
#pragma unroll
                    for (int j = 0; j < 4; j++) {
                        int col = wn + j * 16 + rr;
                        float v = acc[i][j][p] + bias[col];
                        v = (v - mu) * rs * g[col] + be[col];
                        v = v > 0.f ? v : 0.f;
                        xo[(size_t)grow * 128 + col] = f2bf(v);
                    }
                }
            }
        }
    } else {
        int is_bf = (int)flag[0];
#pragma unroll
        for (int i = 0; i < 2; i++) {
#pragma unroll
            for (int p = 0; p < 4; p++) {
                int grow = m0 + wm + i * 16 + qq * 4 + p;
                if (grow < N_NODES) {
#pragma unroll
                    for (int j = 0; j < 4; j++) {
                        int col = wn + j * 16 + rr;
                        float v = acc[i][j][p] + bias[col];
                        if (is_bf) ((unsigned short*)outp)[(size_t)grow * 128 + col] = f2bf(v);
                        else       ((float*)outp)[(size_t)grow * 128 + col] = v;
                    }
                }
            }
        }
    }
}

// ---------------- host ----------------

extern "C" void kernel_launch(void* const* d_in, const int* in_sizes, int n_in,
                              void* d_out, int out_size, void* d_ws, size_t ws_size,
                              hipStream_t stream) {
    const int* node_ids = (const int*)d_in[0];
    const int* ei = (const int*)d_in[1];
    const int* et = (const int*)d_in[2];
    const void* emb = d_in[3];
    const void* W1 = d_in[4];
    const void* r1 = d_in[5];
    const void* b1 = d_in[6];
    const void* g1 = d_in[7];
    const void* be1 = d_in[8];
    const void* W2 = d_in[9];
    const void* r2 = d_in[10];
    const void* b2 = d_in[11];
    const void* g2 = d_in[12];
    const void* be2 = d_in[13];
    const void* W3 = d_in[14];
    const void* r3 = d_in[15];
    const void* b3 = d_in[16];

    char* ws = (char*)d_ws;
    size_t off = 0;
    auto alloc = [&](size_t bytes) -> char* {
        char* p = ws + off;
        off = (off + bytes + 1023) & ~(size_t)1023;
        return p;
    };
    unsigned* cnt_nt  = (unsigned*)alloc((size_t)NSEG2 * 4);
    unsigned* cursor  = (unsigned*)alloc((size_t)NSEG2 * 4);
    size_t zero_end = off;
    unsigned* offs    = (unsigned*)alloc((size_t)(NSEG2 + 1) * 4);
    unsigned* escan   = (unsigned*)alloc((size_t)NSEG2 * 4);
    unsigned* bsum    = (unsigned*)alloc((size_t)SCAN_NB * 4);
    unsigned* boff    = (unsigned*)alloc((size_t)SCAN_NB * 4);
    unsigned* csr     = (unsigned*)alloc((size_t)N_EDGES * 4);
    float* invc       = (float*)alloc((size_t)NSEG2 * 4);
    unsigned short* WcatT = (unsigned short*)alloc((size_t)WELEMS * 2);
    float* vecs       = (float*)alloc((size_t)7 * 128 * 4);
    unsigned* flag    = (unsigned*)alloc(64);
    unsigned short* xa = (unsigned short*)alloc((size_t)N_NODES * 128 * 2);
    unsigned short* xb = (unsigned short*)alloc((size_t)N_NODES * 128 * 2);
    (void)ws_size; (void)in_sizes; (void)n_in; (void)out_size;

    k_init<<<512, 256, 0, stream>>>((unsigned*)ws, (int)(zero_end / 4),
                                    (const unsigned*)g1, flag);
    k_count<<<(N_EDGES + 255) / 256, 256, 0, stream>>>(ei, et, cnt_nt);
    k_scan1<<<SCAN_NB, SCAN_B, 0, stream>>>(cnt_nt, escan, bsum);
    k_scan2<<<1, 512, 0, stream>>>(bsum, boff);
    k_scan3<<<SCAN_NB, SCAN_B, 0, stream>>>(escan, boff, offs, cnt_nt, invc);
    k_fill<<<(N_EDGES + 255) / 256, 256, 0, stream>>>(ei, et, offs, cursor, csr);
    k_prep<<<(WELEMS + 7 * 128 + 255) / 256, 256, 0, stream>>>(
        flag, W1, r1, W2, r2, W3, r3, WcatT, b1, g1, be1, b2, g2, be2, b3, vecs);
    k_gather<<<(N_NODES * 32 + 255) / 256, 256, 0, stream>>>(flag, node_ids, emb, xa);

    // layer 1: xa -> xb
    k_layer<<<NBLK, 256, 0, stream>>>(xa, WcatT + (size_t)0 * 128 * KTOT, offs, csr, invc,
                                      vecs + 0 * 128, vecs + 1 * 128, vecs + 2 * 128,
                                      xb, 1, flag);
    // layer 2: xb -> xa
    k_layer<<<NBLK, 256, 0, stream>>>(xb, WcatT + (size_t)1 * 128 * KTOT, offs, csr, invc,
                                      vecs + 3 * 128, vecs + 4 * 128, vecs + 5 * 128,
                                      xa, 1, flag);
    // layer 3: xa -> d_out (dtype per flag)
    k_layer<<<NBLK, 256, 0, stream>>>(xa, WcatT + (size_t)2 * 128 * KTOT, offs, csr, invc,
                                      vecs + 6 * 128, vecs + 1 * 128, vecs + 2 * 128,
                                      d_out, 0, flag);
}

// Round 6
// 1208.921 us; speedup vs baseline: 2.0439x; 2.0439x over previous
//
#include <hip/hip_runtime.h>
#include <hip/hip_bf16.h>
#include <stdint.h>

// SememeRGCN on MI355X — fully fused per-layer kernel, atomic-free.
// Block owns 64 dst nodes. Edges pre-sorted by (dst/64, t, dst%64) so each
// (block,t,dloc) row range is contiguous in csr. Per relation t, each wave
// owns 16 dst rows and accumulates their means in REGISTERS (lane owns 2
// channels; 16-row round-robin => 16 independent x-row loads in flight, no
// LDS atomics -- r5's generic-pointer atomicAdd compiled to a flat CAS loop
// at ~1000 cyc/edge). Row means written bf16 to the LDS A-tile, then MFMA
// vs W_t staged in LDS. LN+ReLU fused in epilogue. The [N,8,128] mean
// tensor never touches HBM; x (12.8MB) is L2/L3-resident for gathers.

#define N_NODES 50000
#define N_EDGES 800000
#define R_REL 8
#define MT 64                         // nodes per block
#define NBLK ((N_NODES + MT - 1) / MT)          // 782
#define NSEG2 (NBLK * 512)                      // 400384 (block*512 + t*64 + dloc)
#define KTOT 1152
#define AS_S 136                      // A-tile stride (shorts), 16B-aligned rows
#define BS_S 136                      // Bs stride (shorts)

typedef __bf16 bf16_8 __attribute__((ext_vector_type(8)));
typedef float floatx4 __attribute__((ext_vector_type(4)));
typedef unsigned short ushort8 __attribute__((ext_vector_type(8)));

static __device__ __forceinline__ float bf2f(unsigned short v) {
    unsigned u = ((unsigned)v) << 16;
    return __builtin_bit_cast(float, u);
}
static __device__ __forceinline__ unsigned short f2bf(float f) {
    unsigned u = __builtin_bit_cast(unsigned, f);
    u += 0x7FFFu + ((u >> 16) & 1u);   // round-to-nearest-even
    return (unsigned short)(u >> 16);
}

// ---------------- preprocessing ----------------

__global__ void k_init(unsigned* __restrict__ p, int n_words,
                       const unsigned* __restrict__ g1, unsigned* __restrict__ flag) {
    int i = blockIdx.x * blockDim.x + threadIdx.x;
    if (i == 0) flag[0] = (g1[0] == 0x3F803F80u) ? 1u : 0u;
    int stride = gridDim.x * blockDim.x;
    for (; i < n_words; i += stride) p[i] = 0u;
}

__global__ void k_count(const int* __restrict__ ei, const int* __restrict__ et,
                        unsigned* __restrict__ cnt_nt) {
    int e = blockIdx.x * 256 + threadIdx.x;
    if (e >= N_EDGES) return;
    int dst = ei[N_EDGES + e];
    int t = et[e];
    int seg = (dst >> 6) * 512 + t * 64 + (dst & 63);
    atomicAdd(&cnt_nt[seg], 1u);
}

#define SCAN_B 1024
#define SCAN_NB (NSEG2 / SCAN_B)   // 391 exactly

__global__ void k_scan1(const unsigned* __restrict__ cnt, unsigned* __restrict__ escan,
                        unsigned* __restrict__ bsum) {
    __shared__ unsigned wsum[16];
    int tid = threadIdx.x;
    int lane = tid & 63, wid = tid >> 6;
    int i = blockIdx.x * SCAN_B + tid;
    unsigned v = (i < NSEG2) ? cnt[i] : 0u;
    unsigned incl = v;
#pragma unroll
    for (int d = 1; d < 64; d <<= 1) {
        unsigned t = __shfl_up(incl, d, 64);
        if (lane >= d) incl += t;
    }
    if (lane == 63) wsum[wid] = incl;
    __syncthreads();
    if (wid == 0 && lane < 16) {
        unsigned w = wsum[lane];
#pragma unroll
        for (int d = 1; d < 16; d <<= 1) {
            unsigned t = __shfl_up(w, d, 64);
            if (lane >= d) w += t;
        }
        wsum[lane] = w;
    }
    __syncthreads();
    unsigned woff = (wid == 0) ? 0u : wsum[wid - 1];
    if (i < NSEG2) escan[i] = woff + incl - v;
    if (tid == 0) bsum[blockIdx.x] = wsum[15];
}

__global__ void k_scan2(const unsigned* __restrict__ bsum, unsigned* __restrict__ boff) {
    __shared__ unsigned wls[8];
    int tid = threadIdx.x, lane = tid & 63, wid = tid >> 6;   // 512 threads
    unsigned v = (tid < SCAN_NB) ? bsum[tid] : 0u;
    unsigned incl = v;
#pragma unroll
    for (int d = 1; d < 64; d <<= 1) {
        unsigned t = __shfl_up(incl, d, 64);
        if (lane >= d) incl += t;
    }
    if (lane == 63) wls[wid] = incl;
    __syncthreads();
    if (wid == 0 && lane < 8) {
        unsigned w = wls[lane];
#pragma unroll
        for (int d = 1; d < 8; d <<= 1) {
            unsigned t = __shfl_up(w, d, 64);
            if (lane >= d) w += t;
        }
        wls[lane] = w;
    }
    __syncthreads();
    unsigned woff = wid ? wls[wid - 1] : 0u;
    if (tid < SCAN_NB) boff[tid] = woff + incl - v;
}

__global__ void k_scan3(const unsigned* __restrict__ escan, const unsigned* __restrict__ boff,
                        unsigned* __restrict__ offs, const unsigned* __restrict__ cnt,
                        float* __restrict__ invc) {
    int i = blockIdx.x * SCAN_B + threadIdx.x;
    if (i < NSEG2) {
        offs[i] = escan[i] + boff[blockIdx.x];
        unsigned c = cnt[i];
        invc[i] = 1.0f / (float)(c ? c : 1u);
    }
    if (i == 0) offs[NSEG2] = N_EDGES;
}

__global__ void k_fill(const int* __restrict__ ei, const int* __restrict__ et,
                       const unsigned* __restrict__ offs, unsigned* __restrict__ cursor,
                       unsigned* __restrict__ csr) {
    int e = blockIdx.x * 256 + threadIdx.x;
    if (e >= N_EDGES) return;
    int src = ei[e];
    int dst = ei[N_EDGES + e];
    int t = et[e];
    int seg = (dst >> 6) * 512 + t * 64 + (dst & 63);
    unsigned pos = offs[seg] + atomicAdd(&cursor[seg], 1u);
    csr[pos] = (unsigned)src;
}

// merged: WcatT build (transpose to o-major) + 7 param-vector fp32 copies
#define WELEMS (3 * 128 * KTOT)
__global__ void k_prep(const unsigned* __restrict__ flag,
                       const void* __restrict__ W1, const void* __restrict__ r1,
                       const void* __restrict__ W2, const void* __restrict__ r2,
                       const void* __restrict__ W3, const void* __restrict__ r3,
                       unsigned short* __restrict__ WT,
                       const void* p0, const void* p1, const void* p2,
                       const void* p3, const void* p4, const void* p5,
                       const void* p6, float* __restrict__ vecs) {
    int idx = blockIdx.x * 256 + threadIdx.x;
    int is_bf = (int)flag[0];
    if (idx < WELEMS) {
        int l = idx / (128 * KTOT);
        int rem = idx - l * (128 * KTOT);
        int o = rem / KTOT, k = rem - o * KTOT;
        const void* W = (l == 0) ? W1 : (l == 1) ? W2 : W3;
        const void* rt = (l == 0) ? r1 : (l == 1) ? r2 : r3;
        size_t eoff;
        const void* src;
        if (k < 128) { src = rt; eoff = (size_t)k * 128 + o; }
        else {
            int t = (k - 128) >> 7, kk = (k - 128) & 127;
            src = W; eoff = (size_t)t * 16384 + (size_t)kk * 128 + o;
        }
        WT[idx] = is_bf ? ((const unsigned short*)src)[eoff]
                        : f2bf(((const float*)src)[eoff]);
    } else if (idx < WELEMS + 7 * 128) {
        int v = (idx - WELEMS) >> 7, i = (idx - WELEMS) & 127;
        const void* p = (v == 0) ? p0 : (v == 1) ? p1 : (v == 2) ? p2 :
                        (v == 3) ? p3 : (v == 4) ? p4 : (v == 5) ? p5 : p6;
        vecs[v * 128 + i] = is_bf ? bf2f(((const unsigned short*)p)[i])
                                  : ((const float*)p)[i];
    }
}

// gather emb[node_ids] -> xa (bf16)
__global__ void k_gather(const unsigned* __restrict__ flag,
                         const int* __restrict__ ids, const void* __restrict__ emb,
                         unsigned short* __restrict__ x) {
    int c = blockIdx.x * 256 + threadIdx.x;
    if (c >= N_NODES * 32) return;
    int is_bf = (int)flag[0];
    int row = c >> 5, k = (c & 31) << 2;
    size_t s = (size_t)ids[row] * 128 + k;
    if (is_bf) {
        *(uint2*)&x[(size_t)row * 128 + k] = *(const uint2*)((const unsigned short*)emb + s);
    } else {
        const float4 f = *(const float4*)((const float*)emb + s);
        uint2 u;
        u.x = (unsigned)f2bf(f.x) | ((unsigned)f2bf(f.y) << 16);
        u.y = (unsigned)f2bf(f.z) | ((unsigned)f2bf(f.w) << 16);
        *(uint2*)&x[(size_t)row * 128 + k] = u;
    }
}

// ---------------- fused layer kernel ----------------
// grid NBLK (782), 256 threads = 4 waves. LDS: As 17.4KB + Bs 34.8KB + red
// 1KB = 53.2KB -> 3 blocks/CU. wm=(wave&1)*32 (M half), wn=(wave>>1)*64.

__global__ __launch_bounds__(256, 3) void k_layer(
    const unsigned short* __restrict__ x,    // [N,128] bf16 input
    const unsigned short* __restrict__ WT,   // [128 o][1152 k] bf16
    const unsigned* __restrict__ offs,       // [NSEG2+1]
    const unsigned* __restrict__ csr,        // [E] src ids
    const float* __restrict__ invc,          // [NSEG2]
    const float* __restrict__ bias,
    const float* __restrict__ g,
    const float* __restrict__ be,
    void* __restrict__ outp,                 // bf16 x_out or d_out
    int do_ln,
    const unsigned* __restrict__ flag)
{
    __shared__ unsigned short As[MT * AS_S];
    __shared__ unsigned short Bs[128 * BS_S];
    __shared__ float sred[2][MT];
    __shared__ float qred[2][MT];

    int tid = threadIdx.x, b = blockIdx.x;
    int m0 = b * MT;
    int lane = tid & 63, wave = tid >> 6;
    int wm = (wave & 1) * 32, wn = (wave >> 1) * 64;
    int rr = lane & 15, qq = lane >> 4;
    int wnidx = wave >> 1;
    int c0 = lane * 2;

    floatx4 acc[2][4];
#pragma unroll
    for (int i = 0; i < 2; i++)
#pragma unroll
        for (int j = 0; j < 4; j++) acc[i][j] = (floatx4){0.f, 0.f, 0.f, 0.f};

    for (int t = 0; t <= R_REL; ++t) {
        // stage Bs[o][k] = WT[o*1152 + t*128 + k]
#pragma unroll
        for (int it = 0; it < 8; ++it) {
            int c = tid + it * 256;              // 2048 chunks of 8 bf16
            int o = c >> 4, kc = (c & 15) << 3;
            *(ushort8*)&Bs[o * BS_S + kc] = *(const ushort8*)&WT[(size_t)o * KTOT + t * 128 + kc];
        }
        if (t == 0) {
            // root phase: copy x rows (bf16) straight into A-tile
#pragma unroll
            for (int it = 0; it < 4; ++it) {
                int c = tid + it * 256;          // 1024 chunks of 8 shorts
                int row = c >> 4, kc = (c & 15) << 3;
                int grow = m0 + row;
                if (grow >= N_NODES) grow = N_NODES - 1;
                *(ushort8*)&As[row * AS_S + kc] = *(const ushort8*)&x[(size_t)grow * 128 + kc];
            }
        } else {
            // dst-major register accumulation: wave owns 16 contiguous dloc
            // rows; round-robin => up to 16 independent x-row loads in flight.
            int segb = b * 512 + (t - 1) * 64 + (wave << 4);
            unsigned ep[16], en[16];
            float ax[16], ay[16];
#pragma unroll
            for (int i = 0; i < 16; ++i) {
                ep[i] = offs[segb + i];
                en[i] = offs[segb + i + 1];
                ax[i] = 0.f; ay[i] = 0.f;
            }
            bool any = true;
            while (any) {
                any = false;
#pragma unroll
                for (int i = 0; i < 16; ++i) {
                    if (ep[i] < en[i]) {
                        unsigned src = csr[ep[i]++];
                        unsigned u = *(const unsigned*)&x[(size_t)src * 128 + c0];
                        ax[i] += bf2f((unsigned short)(u & 0xFFFFu));
                        ay[i] += bf2f((unsigned short)(u >> 16));
                        any = true;
                    }
                }
            }
#pragma unroll
            for (int i = 0; i < 16; ++i) {
                float w = invc[segb + i];
                unsigned pr = (unsigned)f2bf(ax[i] * w) | ((unsigned)f2bf(ay[i] * w) << 16);
                *(unsigned*)&As[((wave << 4) + i) * AS_S + c0] = pr;
            }
        }
        __syncthreads();

        // MFMA phase
#pragma unroll
        for (int kk = 0; kk < 4; ++kk) {
            int kb = kk * 32 + qq * 8;
            bf16_8 a[2], bfr[4];
#pragma unroll
            for (int i = 0; i < 2; ++i)
                a[i] = __builtin_bit_cast(bf16_8, *(const ushort8*)&As[(wm + i * 16 + rr) * AS_S + kb]);
#pragma unroll
            for (int jj = 0; jj < 4; ++jj)
                bfr[jj] = __builtin_bit_cast(bf16_8, *(const ushort8*)&Bs[(wn + jj * 16 + rr) * BS_S + kb]);
#pragma unroll
            for (int i = 0; i < 2; ++i)
#pragma unroll
                for (int jj = 0; jj < 4; ++jj)
                    acc[i][jj] = __builtin_amdgcn_mfma_f32_16x16x32_bf16(a[i], bfr[jj], acc[i][jj], 0, 0, 0);
        }
        __syncthreads();
    }

    // ---------------- epilogue ----------------
    if (do_ln) {
#pragma unroll
        for (int i = 0; i < 2; i++) {
#pragma unroll
            for (int p = 0; p < 4; p++) {
                float s1 = 0.f, s2 = 0.f;
#pragma unroll
                for (int j = 0; j < 4; j++) {
                    float v = acc[i][j][p] + bias[wn + j * 16 + rr];
                    s1 += v; s2 += v * v;
                }
#pragma unroll
                for (int d = 1; d < 16; d <<= 1) {
                    s1 += __shfl_xor(s1, d, 64);
                    s2 += __shfl_xor(s2, d, 64);
                }
                if (rr == 0) {
                    int rl = wm + i * 16 + qq * 4 + p;
                    sred[wnidx][rl] = s1;
                    qred[wnidx][rl] = s2;
                }
            }
        }
        __syncthreads();
        unsigned short* xo = (unsigned short*)outp;
#pragma unroll
        for (int i = 0; i < 2; i++) {
#pragma unroll
            for (int p = 0; p < 4; p++) {
                int rl = wm + i * 16 + qq * 4 + p;
                int grow = m0 + rl;
                float s1 = sred[0][rl] + sred[1][rl];
                float s2 = qred[0][rl] + qred[1][rl];
                float mu = s1 * (1.f / 128.f);
                float var = s2 * (1.f / 128.f) - mu * mu;
                float rs = rsqrtf(var + 1e-5f);
                if (grow < N_NODES) {
#pragma unroll
                    for (int j = 0; j < 4; j++) {
                        int col = wn + j * 16 + rr;
                        float v = acc[i][j][p] + bias[col];
                        v = (v - mu) * rs * g[col] + be[col];
                        v = v > 0.f ? v : 0.f;
                        xo[(size_t)grow * 128 + col] = f2bf(v);
                    }
                }
            }
        }
    } else {
        int is_bf = (int)flag[0];
#pragma unroll
        for (int i = 0; i < 2; i++) {
#pragma unroll
            for (int p = 0; p < 4; p++) {
                int grow = m0 + wm + i * 16 + qq * 4 + p;
                if (grow < N_NODES) {
#pragma unroll
                    for (int j = 0; j < 4; j++) {
                        int col = wn + j * 16 + rr;
                        float v = acc[i][j][p] + bias[col];
                        if (is_bf) ((unsigned short*)outp)[(size_t)grow * 128 + col] = f2bf(v);
                        else       ((float*)outp)[(size_t)grow * 128 + col] = v;
                    }
                }
            }
        }
    }
}

// ---------------- host ----------------

extern "C" void kernel_launch(void* const* d_in, const int* in_sizes, int n_in,
                              void* d_out, int out_size, void* d_ws, size_t ws_size,
                              hipStream_t stream) {
    const int* node_ids = (const int*)d_in[0];
    const int* ei = (const int*)d_in[1];
    const int* et = (const int*)d_in[2];
    const void* emb = d_in[3];
    const void* W1 = d_in[4];
    const void* r1 = d_in[5];
    const void* b1 = d_in[6];
    const void* g1 = d_in[7];
    const void* be1 = d_in[8];
    const void* W2 = d_in[9];
    const void* r2 = d_in[10];
    const void* b2 = d_in[11];
    const void* g2 = d_in[12];
    const void* be2 = d_in[13];
    const void* W3 = d_in[14];
    const void* r3 = d_in[15];
    const void* b3 = d_in[16];

    char* ws = (char*)d_ws;
    size_t off = 0;
    auto alloc = [&](size_t bytes) -> char* {
        char* p = ws + off;
        off = (off + bytes + 1023) & ~(size_t)1023;
        return p;
    };
    unsigned* cnt_nt  = (unsigned*)alloc((size_t)NSEG2 * 4);
    unsigned* cursor  = (unsigned*)alloc((size_t)NSEG2 * 4);
    size_t zero_end = off;
    unsigned* offs    = (unsigned*)alloc((size_t)(NSEG2 + 1) * 4);
    unsigned* escan   = (unsigned*)alloc((size_t)NSEG2 * 4);
    unsigned* bsum    = (unsigned*)alloc((size_t)SCAN_NB * 4);
    unsigned* boff    = (unsigned*)alloc((size_t)SCAN_NB * 4);
    unsigned* csr     = (unsigned*)alloc((size_t)N_EDGES * 4);
    float* invc       = (float*)alloc((size_t)NSEG2 * 4);
    unsigned short* WcatT = (unsigned short*)alloc((size_t)WELEMS * 2);
    float* vecs       = (float*)alloc((size_t)7 * 128 * 4);
    unsigned* flag    = (unsigned*)alloc(64);
    unsigned short* xa = (unsigned short*)alloc((size_t)N_NODES * 128 * 2);
    unsigned short* xb = (unsigned short*)alloc((size_t)N_NODES * 128 * 2);
    (void)ws_size; (void)in_sizes; (void)n_in; (void)out_size;

    k_init<<<512, 256, 0, stream>>>((unsigned*)ws, (int)(zero_end / 4),
                                    (const unsigned*)g1, flag);
    k_count<<<(N_EDGES + 255) / 256, 256, 0, stream>>>(ei, et, cnt_nt);
    k_scan1<<<SCAN_NB, SCAN_B, 0, stream>>>(cnt_nt, escan, bsum);
    k_scan2<<<1, 512, 0, stream>>>(bsum, boff);
    k_scan3<<<SCAN_NB, SCAN_B, 0, stream>>>(escan, boff, offs, cnt_nt, invc);
    k_fill<<<(N_EDGES + 255) / 256, 256, 0, stream>>>(ei, et, offs, cursor, csr);
    k_prep<<<(WELEMS + 7 * 128 + 255) / 256, 256, 0, stream>>>(
        flag, W1, r1, W2, r2, W3, r3, WcatT, b1, g1, be1, b2, g2, be2, b3, vecs);
    k_gather<<<(N_NODES * 32 + 255) / 256, 256, 0, stream>>>(flag, node_ids, emb, xa);

    // layer 1: xa -> xb
    k_layer<<<NBLK, 256, 0, stream>>>(xa, WcatT + (size_t)0 * 128 * KTOT, offs, csr, invc,
                                      vecs + 0 * 128, vecs + 1 * 128, vecs + 2 * 128,
                                      xb, 1, flag);
    // layer 2: xb -> xa
    k_layer<<<NBLK, 256, 0, stream>>>(xb, WcatT + (size_t)1 * 128 * KTOT, offs, csr, invc,
                                      vecs + 3 * 128, vecs + 4 * 128, vecs + 5 * 128,
                                      xa, 1, flag);
    // layer 3: xa -> d_out (dtype per flag)
    k_layer<<<NBLK, 256, 0, stream>>>(xa, WcatT + (size_t)2 * 128 * KTOT, offs, csr, invc,
                                      vecs + 6 * 128, vecs + 1 * 128, vecs + 2 * 128,
                                      d_out, 0, flag);
}

// Round 7
// 589.234 us; speedup vs baseline: 4.1933x; 2.0517x over previous
//
#include <hip/hip_runtime.h>
#include <hip/hip_bf16.h>
#include <stdint.h>

// SememeRGCN on MI355X — fully fused per-layer kernel, atomic-free.
// Block owns 64 dst nodes. Edges pre-sorted by (dst/64, t, dst%64) so each
// (block,t,dloc) row range is contiguous in csr. Per relation t, each wave
// owns 16 dst rows; gather is BRANCHLESS and scalar-controlled:
//   - segb via readfirstlane -> offsets/counts/loop bound in SGPRs
//   - padded loop to maxc (max row count in the wave's 16 rows); inactive
//     iterations read csr[0] and are squashed with cndmask on the value
//   - next iteration's 16 csr indices prefetched before this iteration's 16
//     independent x-row loads -> 16 loads in flight, no exec-mask branches
// (r6 bug: per-row `if` bodies forced one serialized ~600cy csr->x chain per
// edge). Row means written bf16 to LDS A-tile, MFMA vs W_t, LN+ReLU fused.

#define N_NODES 50000
#define N_EDGES 800000
#define R_REL 8
#define MT 64                         // nodes per block
#define NBLK ((N_NODES + MT - 1) / MT)          // 782
#define NSEG2 (NBLK * 512)                      // 400384 (block*512 + t*64 + dloc)
#define KTOT 1152
#define AS_S 136                      // A-tile stride (shorts), 16B-aligned rows
#define BS_S 136                      // Bs stride (shorts)

typedef __bf16 bf16_8 __attribute__((ext_vector_type(8)));
typedef float floatx4 __attribute__((ext_vector_type(4)));
typedef unsigned short ushort8 __attribute__((ext_vector_type(8)));

static __device__ __forceinline__ float bf2f(unsigned short v) {
    unsigned u = ((unsigned)v) << 16;
    return __builtin_bit_cast(float, u);
}
static __device__ __forceinline__ unsigned short f2bf(float f) {
    unsigned u = __builtin_bit_cast(unsigned, f);
    u += 0x7FFFu + ((u >> 16) & 1u);   // round-to-nearest-even
    return (unsigned short)(u >> 16);
}

// ---------------- preprocessing ----------------

__global__ void k_init(unsigned* __restrict__ p, int n_words,
                       const unsigned* __restrict__ g1, unsigned* __restrict__ flag) {
    int i = blockIdx.x * blockDim.x + threadIdx.x;
    if (i == 0) flag[0] = (g1[0] == 0x3F803F80u) ? 1u : 0u;
    int stride = gridDim.x * blockDim.x;
    for (; i < n_words; i += stride) p[i] = 0u;
}

__global__ void k_count(const int* __restrict__ ei, const int* __restrict__ et,
                        unsigned* __restrict__ cnt_nt) {
    int e = blockIdx.x * 256 + threadIdx.x;
    if (e >= N_EDGES) return;
    int dst = ei[N_EDGES + e];
    int t = et[e];
    int seg = (dst >> 6) * 512 + t * 64 + (dst & 63);
    atomicAdd(&cnt_nt[seg], 1u);
}

#define SCAN_B 1024
#define SCAN_NB (NSEG2 / SCAN_B)   // 391 exactly

__global__ void k_scan1(const unsigned* __restrict__ cnt, unsigned* __restrict__ escan,
                        unsigned* __restrict__ bsum) {
    __shared__ unsigned wsum[16];
    int tid = threadIdx.x;
    int lane = tid & 63, wid = tid >> 6;
    int i = blockIdx.x * SCAN_B + tid;
    unsigned v = (i < NSEG2) ? cnt[i] : 0u;
    unsigned incl = v;
#pragma unroll
    for (int d = 1; d < 64; d <<= 1) {
        unsigned t = __shfl_up(incl, d, 64);
        if (lane >= d) incl += t;
    }
    if (lane == 63) wsum[wid] = incl;
    __syncthreads();
    if (wid == 0 && lane < 16) {
        unsigned w = wsum[lane];
#pragma unroll
        for (int d = 1; d < 16; d <<= 1) {
            unsigned t = __shfl_up(w, d, 64);
            if (lane >= d) w += t;
        }
        wsum[lane] = w;
    }
    __syncthreads();
    unsigned woff = (wid == 0) ? 0u : wsum[wid - 1];
    if (i < NSEG2) escan[i] = woff + incl - v;
    if (tid == 0) bsum[blockIdx.x] = wsum[15];
}

__global__ void k_scan2(const unsigned* __restrict__ bsum, unsigned* __restrict__ boff) {
    __shared__ unsigned wls[8];
    int tid = threadIdx.x, lane = tid & 63, wid = tid >> 6;   // 512 threads
    unsigned v = (tid < SCAN_NB) ? bsum[tid] : 0u;
    unsigned incl = v;
#pragma unroll
    for (int d = 1; d < 64; d <<= 1) {
        unsigned t = __shfl_up(incl, d, 64);
        if (lane >= d) incl += t;
    }
    if (lane == 63) wls[wid] = incl;
    __syncthreads();
    if (wid == 0 && lane < 8) {
        unsigned w = wls[lane];
#pragma unroll
        for (int d = 1; d < 8; d <<= 1) {
            unsigned t = __shfl_up(w, d, 64);
            if (lane >= d) w += t;
        }
        wls[lane] = w;
    }
    __syncthreads();
    unsigned woff = wid ? wls[wid - 1] : 0u;
    if (tid < SCAN_NB) boff[tid] = woff + incl - v;
}

__global__ void k_scan3(const unsigned* __restrict__ escan, const unsigned* __restrict__ boff,
                        unsigned* __restrict__ offs, const unsigned* __restrict__ cnt,
                        float* __restrict__ invc) {
    int i = blockIdx.x * SCAN_B + threadIdx.x;
    if (i < NSEG2) {
        offs[i] = escan[i] + boff[blockIdx.x];
        unsigned c = cnt[i];
        invc[i] = 1.0f / (float)(c ? c : 1u);
    }
    if (i == 0) offs[NSEG2] = N_EDGES;
}

__global__ void k_fill(const int* __restrict__ ei, const int* __restrict__ et,
                       const unsigned* __restrict__ offs, unsigned* __restrict__ cursor,
                       unsigned* __restrict__ csr) {
    int e = blockIdx.x * 256 + threadIdx.x;
    if (e >= N_EDGES) return;
    int src = ei[e];
    int dst = ei[N_EDGES + e];
    int t = et[e];
    int seg = (dst >> 6) * 512 + t * 64 + (dst & 63);
    unsigned pos = offs[seg] + atomicAdd(&cursor[seg], 1u);
    csr[pos] = (unsigned)src;
}

// merged: WcatT build (transpose to o-major) + 7 param-vector fp32 copies
#define WELEMS (3 * 128 * KTOT)
__global__ void k_prep(const unsigned* __restrict__ flag,
                       const void* __restrict__ W1, const void* __restrict__ r1,
                       const void* __restrict__ W2, const void* __restrict__ r2,
                       const void* __restrict__ W3, const void* __restrict__ r3,
                       unsigned short* __restrict__ WT,
                       const void* p0, const void* p1, const void* p2,
                       const void* p3, const void* p4, const void* p5,
                       const void* p6, float* __restrict__ vecs) {
    int idx = blockIdx.x * 256 + threadIdx.x;
    int is_bf = (int)flag[0];
    if (idx < WELEMS) {
        int l = idx / (128 * KTOT);
        int rem = idx - l * (128 * KTOT);
        int o = rem / KTOT, k = rem - o * KTOT;
        const void* W = (l == 0) ? W1 : (l == 1) ? W2 : W3;
        const void* rt = (l == 0) ? r1 : (l == 1) ? r2 : r3;
        size_t eoff;
        const void* src;
        if (k < 128) { src = rt; eoff = (size_t)k * 128 + o; }
        else {
            int t = (k - 128) >> 7, kk = (k - 128) & 127;
            src = W; eoff = (size_t)t * 16384 + (size_t)kk * 128 + o;
        }
        WT[idx] = is_bf ? ((const unsigned short*)src)[eoff]
                        : f2bf(((const float*)src)[eoff]);
    } else if (idx < WELEMS + 7 * 128) {
        int v = (idx - WELEMS) >> 7, i = (idx - WELEMS) & 127;
        const void* p = (v == 0) ? p0 : (v == 1) ? p1 : (v == 2) ? p2 :
                        (v == 3) ? p3 : (v == 4) ? p4 : (v == 5) ? p5 : p6;
        vecs[v * 128 + i] = is_bf ? bf2f(((const unsigned short*)p)[i])
                                  : ((const float*)p)[i];
    }
}

// gather emb[node_ids] -> xa (bf16)
__global__ void k_gather(const unsigned* __restrict__ flag,
                         const int* __restrict__ ids, const void* __restrict__ emb,
                         unsigned short* __restrict__ x) {
    int c = blockIdx.x * 256 + threadIdx.x;
    if (c >= N_NODES * 32) return;
    int is_bf = (int)flag[0];
    int row = c >> 5, k = (c & 31) << 2;
    size_t s = (size_t)ids[row] * 128 + k;
    if (is_bf) {
        *(uint2*)&x[(size_t)row * 128 + k] = *(const uint2*)((const unsigned short*)emb + s);
    } else {
        const float4 f = *(const float4*)((const float*)emb + s);
        uint2 u;
        u.x = (unsigned)f2bf(f.x) | ((unsigned)f2bf(f.y) << 16);
        u.y = (unsigned)f2bf(f.z) | ((unsigned)f2bf(f.w) << 16);
        *(uint2*)&x[(size_t)row * 128 + k] = u;
    }
}

// ---------------- fused layer kernel ----------------
// grid NBLK (782), 256 threads = 4 waves. LDS: As 17.4KB + Bs 34.8KB + red
// 1KB = 53.2KB -> 3 blocks/CU. wm=(wave&1)*32 (M half), wn=(wave>>1)*64.

__global__ __launch_bounds__(256, 3) void k_layer(
    const unsigned short* __restrict__ x,    // [N,128] bf16 input
    const unsigned short* __restrict__ WT,   // [128 o][1152 k] bf16
    const unsigned* __restrict__ offs,       // [NSEG2+1]
    const unsigned* __restrict__ csr,        // [E] src ids
    const float* __restrict__ invc,          // [NSEG2]
    const float* __restrict__ bias,
    const float* __restrict__ g,
    const float* __restrict__ be,
    void* __restrict__ outp,                 // bf16 x_out or d_out
    int do_ln,
    const unsigned* __restrict__ flag)
{
    __shared__ unsigned short As[MT * AS_S];
    __shared__ unsigned short Bs[128 * BS_S];
    __shared__ float sred[2][MT];
    __shared__ float qred[2][MT];

    int tid = threadIdx.x, b = blockIdx.x;
    int m0 = b * MT;
    int lane = tid & 63, wave = tid >> 6;
    int wm = (wave & 1) * 32, wn = (wave >> 1) * 64;
    int rr = lane & 15, qq = lane >> 4;
    int wnidx = wave >> 1;
    int c0 = lane * 2;

    floatx4 acc[2][4];
#pragma unroll
    for (int i = 0; i < 2; i++)
#pragma unroll
        for (int j = 0; j < 4; j++) acc[i][j] = (floatx4){0.f, 0.f, 0.f, 0.f};

    for (int t = 0; t <= R_REL; ++t) {
        // stage Bs[o][k] = WT[o*1152 + t*128 + k]
#pragma unroll
        for (int it = 0; it < 8; ++it) {
            int c = tid + it * 256;              // 2048 chunks of 8 bf16
            int o = c >> 4, kc = (c & 15) << 3;
            *(ushort8*)&Bs[o * BS_S + kc] = *(const ushort8*)&WT[(size_t)o * KTOT + t * 128 + kc];
        }
        if (t == 0) {
            // root phase: copy x rows (bf16) straight into A-tile
#pragma unroll
            for (int it = 0; it < 4; ++it) {
                int c = tid + it * 256;          // 1024 chunks of 8 shorts
                int row = c >> 4, kc = (c & 15) << 3;
                int grow = m0 + row;
                if (grow >= N_NODES) grow = N_NODES - 1;
                *(ushort8*)&As[row * AS_S + kc] = *(const ushort8*)&x[(size_t)grow * 128 + kc];
            }
        } else {
            // branchless scalar-controlled gather, 16 rows per wave
            int segb = __builtin_amdgcn_readfirstlane(b * 512 + (t - 1) * 64 + (wave << 4));
            int ep[16], cnt[16];
            int maxc = 0;
            {
                int prev = (int)offs[segb];
#pragma unroll
                for (int i = 0; i < 16; ++i) {
                    int nxt = (int)offs[segb + i + 1];
                    ep[i] = prev;
                    cnt[i] = nxt - prev;
                    maxc = max(maxc, cnt[i]);
                    prev = nxt;
                }
            }
            maxc = __builtin_amdgcn_readfirstlane(maxc);
            float ax[16], ay[16];
#pragma unroll
            for (int i = 0; i < 16; ++i) { ax[i] = 0.f; ay[i] = 0.f; }

            unsigned srcs[16];
#pragma unroll
            for (int i = 0; i < 16; ++i)
                srcs[i] = csr[(0 < cnt[i]) ? ep[i] : 0];

            for (int r = 0; r < maxc; ++r) {
                // prefetch next iteration's csr indices
                unsigned nsrcs[16];
#pragma unroll
                for (int i = 0; i < 16; ++i)
                    nsrcs[i] = csr[(r + 1 < cnt[i]) ? (ep[i] + r + 1) : 0];
                // 16 independent x-row loads
                unsigned uv[16];
#pragma unroll
                for (int i = 0; i < 16; ++i)
                    uv[i] = *(const unsigned*)&x[(size_t)srcs[i] * 128 + c0];
#pragma unroll
                for (int i = 0; i < 16; ++i) {
                    float vx = bf2f((unsigned short)(uv[i] & 0xFFFFu));
                    float vy = bf2f((unsigned short)(uv[i] >> 16));
                    bool on = r < cnt[i];
                    ax[i] += on ? vx : 0.f;
                    ay[i] += on ? vy : 0.f;
                }
#pragma unroll
                for (int i = 0; i < 16; ++i) srcs[i] = nsrcs[i];
            }
#pragma unroll
            for (int i = 0; i < 16; ++i) {
                float w = invc[segb + i];
                unsigned pr = (unsigned)f2bf(ax[i] * w) | ((unsigned)f2bf(ay[i] * w) << 16);
                *(unsigned*)&As[((wave << 4) + i) * AS_S + c0] = pr;
            }
        }
        __syncthreads();

        // MFMA phase
#pragma unroll
        for (int kk = 0; kk < 4; ++kk) {
            int kb = kk * 32 + qq * 8;
            bf16_8 a[2], bfr[4];
#pragma unroll
            for (int i = 0; i < 2; ++i)
                a[i] = __builtin_bit_cast(bf16_8, *(const ushort8*)&As[(wm + i * 16 + rr) * AS_S + kb]);
#pragma unroll
            for (int jj = 0; jj < 4; ++jj)
                bfr[jj] = __builtin_bit_cast(bf16_8, *(const ushort8*)&Bs[(wn + jj * 16 + rr) * BS_S + kb]);
#pragma unroll
            for (int i = 0; i < 2; ++i)
#pragma unroll
                for (int jj = 0; jj < 4; ++jj)
                    acc[i][jj] = __builtin_amdgcn_mfma_f32_16x16x32_bf16(a[i], bfr[jj], acc[i][jj], 0, 0, 0);
        }
        __syncthreads();
    }

    // ---------------- epilogue ----------------
    if (do_ln) {
#pragma unroll
        for (int i = 0; i < 2; i++) {
#pragma unroll
            for (int p = 0; p < 4; p++) {
                float s1 = 0.f, s2 = 0.f;
#pragma unroll
                for (int j = 0; j < 4; j++) {
                    float v = acc[i][j][p] + bias[wn + j * 16 + rr];
                    s1 += v; s2 += v * v;
                }
#pragma unroll
                for (int d = 1; d < 16; d <<= 1) {
                    s1 += __shfl_xor(s1, d, 64);
                    s2 += __shfl_xor(s2, d, 64);
                }
                if (rr == 0) {
                    int rl = wm + i * 16 + qq * 4 + p;
                    sred[wnidx][rl] = s1;
                    qred[wnidx][rl] = s2;
                }
            }
        }
        __syncthreads();
        unsigned short* xo = (unsigned short*)outp;
#pragma unroll
        for (int i = 0; i < 2; i++) {
#pragma unroll
            for (int p = 0; p < 4; p++) {
                int rl = wm + i * 16 + qq * 4 + p;
                int grow = m0 + rl;
                float s1 = sred[0][rl] + sred[1][rl];
                float s2 = qred[0][rl] + qred[1][rl];
                float mu = s1 * (1.f / 128.f);
                float var = s2 * (1.f / 128.f) - mu * mu;
                float rs = rsqrtf(var + 1e-5f);
                if (grow < N_NODES) {
#pragma unroll
                    for (int j = 0; j < 4; j++) {
                        int col = wn + j * 16 + rr;
                        float v = acc[i][j][p] + bias[col];
                        v = (v - mu) * rs * g[col] + be[col];
                        v = v > 0.f ? v : 0.f;
                        xo[(size_t)grow * 128 + col] = f2bf(v);
                    }
                }
            }
        }
    } else {
        int is_bf = (int)flag[0];
#pragma unroll
        for (int i = 0; i < 2; i++) {
#pragma unroll
            for (int p = 0; p < 4; p++) {
                int grow = m0 + wm + i * 16 + qq * 4 + p;
                if (grow < N_NODES) {
#pragma unroll
                    for (int j = 0; j < 4; j++) {
                        int col = wn + j * 16 + rr;
                        float v = acc[i][j][p] + bias[col];
                        if (is_bf) ((unsigned short*)outp)[(size_t)grow * 128 + col] = f2bf(v);
                        else       ((float*)outp)[(size_t)grow * 128 + col] = v;
                    }
                }
            }
        }
    }
}

// ---------------- host ----------------

extern "C" void kernel_launch(void* const* d_in, const int* in_sizes, int n_in,
                              void* d_out, int out_size, void* d_ws, size_t ws_size,
                              hipStream_t stream) {
    const int* node_ids = (const int*)d_in[0];
    const int* ei = (const int*)d_in[1];
    const int* et = (const int*)d_in[2];
    const void* emb = d_in[3];
    const void* W1 = d_in[4];
    const void* r1 = d_in[5];
    const void* b1 = d_in[6];
    const void* g1 = d_in[7];
    const void* be1 = d_in[8];
    const void* W2 = d_in[9];
    const void* r2 = d_in[10];
    const void* b2 = d_in[11];
    const void* g2 = d_in[12];
    const void* be2 = d_in[13];
    const void* W3 = d_in[14];
    const void* r3 = d_in[15];
    const void* b3 = d_in[16];

    char* ws = (char*)d_ws;
    size_t off = 0;
    auto alloc = [&](size_t bytes) -> char* {
        char* p = ws + off;
        off = (off + bytes + 1023) & ~(size_t)1023;
        return p;
    };
    unsigned* cnt_nt  = (unsigned*)alloc((size_t)NSEG2 * 4);
    unsigned* cursor  = (unsigned*)alloc((size_t)NSEG2 * 4);
    size_t zero_end = off;
    unsigned* offs    = (unsigned*)alloc((size_t)(NSEG2 + 1) * 4);
    unsigned* escan   = (unsigned*)alloc((size_t)NSEG2 * 4);
    unsigned* bsum    = (unsigned*)alloc((size_t)SCAN_NB * 4);
    unsigned* boff    = (unsigned*)alloc((size_t)SCAN_NB * 4);
    unsigned* csr     = (unsigned*)alloc((size_t)N_EDGES * 4);
    float* invc       = (float*)alloc((size_t)NSEG2 * 4);
    unsigned short* WcatT = (unsigned short*)alloc((size_t)WELEMS * 2);
    float* vecs       = (float*)alloc((size_t)7 * 128 * 4);
    unsigned* flag    = (unsigned*)alloc(64);
    unsigned short* xa = (unsigned short*)alloc((size_t)N_NODES * 128 * 2);
    unsigned short* xb = (unsigned short*)alloc((size_t)N_NODES * 128 * 2);
    (void)ws_size; (void)in_sizes; (void)n_in; (void)out_size;

    k_init<<<512, 256, 0, stream>>>((unsigned*)ws, (int)(zero_end / 4),
                                    (const unsigned*)g1, flag);
    k_count<<<(N_EDGES + 255) / 256, 256, 0, stream>>>(ei, et, cnt_nt);
    k_scan1<<<SCAN_NB, SCAN_B, 0, stream>>>(cnt_nt, escan, bsum);
    k_scan2<<<1, 512, 0, stream>>>(bsum, boff);
    k_scan3<<<SCAN_NB, SCAN_B, 0, stream>>>(escan, boff, offs, cnt_nt, invc);
    k_fill<<<(N_EDGES + 255) / 256, 256, 0, stream>>>(ei, et, offs, cursor, csr);
    k_prep<<<(WELEMS + 7 * 128 + 255) / 256, 256, 0, stream>>>(
        flag, W1, r1, W2, r2, W3, r3, WcatT, b1, g1, be1, b2, g2, be2, b3, vecs);
    k_gather<<<(N_NODES * 32 + 255) / 256, 256, 0, stream>>>(flag, node_ids, emb, xa);

    // layer 1: xa -> xb
    k_layer<<<NBLK, 256, 0, stream>>>(xa, WcatT + (size_t)0 * 128 * KTOT, offs, csr, invc,
                                      vecs + 0 * 128, vecs + 1 * 128, vecs + 2 * 128,
                                      xb, 1, flag);
    // layer 2: xb -> xa
    k_layer<<<NBLK, 256, 0, stream>>>(xb, WcatT + (size_t)1 * 128 * KTOT, offs, csr, invc,
                                      vecs + 3 * 128, vecs + 4 * 128, vecs + 5 * 128,
                                      xa, 1, flag);
    // layer 3: xa -> d_out (dtype per flag)
    k_layer<<<NBLK, 256, 0, stream>>>(xa, WcatT + (size_t)2 * 128 * KTOT, offs, csr, invc,
                                      vecs + 6 * 128, vecs + 1 * 128, vecs + 2 * 128,
                                      d_out, 0, flag);
}